// Round 6
// baseline (494.717 us; speedup 1.0000x reference)
//
#include <hip/hip_runtime.h>
#include <hip/hip_bf16.h>

// Problem constants (CrossNetMixFuxiCTR): B=16384, D=2048, L=3, E=8, R=64
#define BDIM 16384
#define DDIM 2048
#define LNUM 3
#define ENUM 8
#define NP 24            // L*E (l,e) pairs

// GEMM tile (8-wave pipelined template)
#define BM 256           // A rows per block
#define BK 64            // f16 k-elements per tile (128 B/row)
#define NT (DDIM / BK)   // 32 K-tiles

typedef _Float16 f16x8 __attribute__((ext_vector_type(8)));
typedef _Float16 f16x4 __attribute__((ext_vector_type(4)));
typedef float f32x4 __attribute__((ext_vector_type(4)));

// ------- convert U,V -> Wh f16, layout [p=24][128 rows: 64 U then 64 V][D] -------
__global__ void cvt_w_kernel(const float* __restrict__ U, const float* __restrict__ V,
                             _Float16* __restrict__ Wh) {
    size_t f = (size_t)blockIdx.x * blockDim.x + threadIdx.x;   // float4 index
    size_t elem = f * 4;
    int d   = (int)(elem & (DDIM - 1));
    int row = (int)((elem >> 11) & 127);   // /2048 % 128
    int p   = (int)(elem >> 18);           // /(2048*128)
    const float* src = (row < 64)
        ? (U + ((size_t)(p * 64 + row) * DDIM + d))
        : (V + ((size_t)(p * 64 + (row - 64)) * DDIM + d));
    float4 v = *(const float4*)src;
    f16x4 h = { (_Float16)v.x, (_Float16)v.y, (_Float16)v.z, (_Float16)v.w };
    ((f16x4*)Wh)[f] = h;
}

// ------- convert X0 f32 -> X0h f16 (memory-bound) -------
__global__ void cvt_x_kernel(const float* __restrict__ X0, _Float16* __restrict__ X0h) {
    size_t f = (size_t)blockIdx.x * blockDim.x + threadIdx.x;   // float4 index
    float4 v = ((const float4*)X0)[f];
    f16x4 h = { (_Float16)v.x, (_Float16)v.y, (_Float16)v.z, (_Float16)v.w };
    ((f16x4*)X0h)[f] = h;
}

// ---------------- pipelined MFMA GEMM + in-wave bilinear reduction ----------------
// 512 thr = 8 waves (wm = wave>>1 in 0..3, wn = wave&1). Tile: 256 rows x 256 cols
// (= TWO p-slices; slice p = 2*by + wn, 128 cols: 0-63 PU, 64-127 PV).
// R5: gate slice REMOVED (now in epilogue) -> grid (64,12) = 768 blocks = EXACTLY
// 3 occupancy rounds at 1 block/CU (was 832 = 3.25 -> 4 rounds, 19% idle tail).
// Outer schedule (verified R3/R4): dbuf 128 KiB LDS, 2 K-tiles in flight, vmcnt(8)
// counted wait + 2 raw s_barrier per tile; never drains vmcnt to 0 in main loop.
// LDS swizzle: 16B chunk c of row r stored at c ^ (r&7); applied on the pre-swizzled
// GLOBAL source address (linear LDS dest, rule #21) and on the ds_read addr.
__global__ __launch_bounds__(512, 2) void gemm_t_kernel(
    const _Float16* __restrict__ Ah,   // [BDIM][DDIM] f16
    const _Float16* __restrict__ Bh,   // [NP][128][DDIM] f16
    float* __restrict__ T)             // [NP][BDIM]
{
    const int by   = blockIdx.y;          // 0..11 slice pairs
    const int m0   = blockIdx.x * BM;
    const int tid  = (int)threadIdx.x;
    const int wave = tid >> 6;
    const int lane = tid & 63;
    const int wm   = wave >> 1;           // 0..3 row quadrant
    const int wn   = wave & 1;            // 0/1 slice within pair
    const int mlane = lane & 15;
    const int quad  = lane >> 4;

    // [buf][A/B][256 rows * 64 f16] = 128 KiB
    __shared__ _Float16 Ls[2][2][BM * BK];

    // ---- per-thread staging source pointers (pre-swizzled global addresses) ----
    const _Float16* aptr[4];
    const _Float16* bptr[4];
#pragma unroll
    for (int q = 0; q < 4; ++q) {
        int idx = q * 512 + tid;          // 16B-chunk index 0..2047
        int row = idx >> 3;               // 0..255
        int c   = idx & 7;
        int col = ((c ^ (row & 7)) * 8);  // swizzled f16 column within the 64-wide tile
        aptr[q] = Ah + (size_t)(m0 + row) * DDIM + col;
        int s = row >> 7;                 // which slice of the pair
        int brow = row & 127;
        bptr[q] = Bh + (size_t)(2 * by + s) * 128 * DDIM + (size_t)brow * DDIM + col;
    }

    f32x4 acc[4][8];
#pragma unroll
    for (int i = 0; i < 4; ++i)
#pragma unroll
        for (int j = 0; j < 8; ++j) acc[i][j] = (f32x4){0.f, 0.f, 0.f, 0.f};

    // ---- prologue: stage tiles 0 and 1 ----
#pragma unroll
    for (int tt = 0; tt < 2; ++tt) {
#pragma unroll
        for (int q = 0; q < 4; ++q)
            __builtin_amdgcn_global_load_lds(
                (const __attribute__((address_space(1))) void*)(aptr[q] + tt * BK),
                (__attribute__((address_space(3))) void*)&Ls[tt][0][(q * 512 + wave * 64) * 8],
                16, 0, 0);
#pragma unroll
        for (int q = 0; q < 4; ++q)
            __builtin_amdgcn_global_load_lds(
                (const __attribute__((address_space(1))) void*)(bptr[q] + tt * BK),
                (__attribute__((address_space(3))) void*)&Ls[tt][1][(q * 512 + wave * 64) * 8],
                16, 0, 0);
    }

    int cur = 0;
    for (int t = 0; t < NT; ++t) {
        // own tile-t loads landed (tile t+1's 8 stay in flight); barrier -> block-wide
        if (t < NT - 1) asm volatile("s_waitcnt vmcnt(8)" ::: "memory");
        else            asm volatile("s_waitcnt vmcnt(0)" ::: "memory");
        __builtin_amdgcn_s_barrier();

        const _Float16* Asc = &Ls[cur][0][0];
        const _Float16* Bsc = &Ls[cur][1][0];

        f16x8 a0[4], a1[4], bx[4], by8[4];
        // q0 reads: A ks0 (4) + B ks0 n0-3 (4)
#pragma unroll
        for (int mi = 0; mi < 4; ++mi) {
            int row = wm * 64 + mi * 16 + mlane;
            a0[mi] = *(const f16x8*)&Asc[row * BK + ((quad ^ (row & 7)) * 8)];
        }
#pragma unroll
        for (int ni = 0; ni < 4; ++ni) {
            int row = wn * 128 + ni * 16 + mlane;
            bx[ni] = *(const f16x8*)&Bsc[row * BK + ((quad ^ (row & 7)) * 8)];
        }
#pragma unroll
        for (int ni = 0; ni < 4; ++ni) {
            int row = wn * 128 + (ni + 4) * 16 + mlane;
            by8[ni] = *(const f16x8*)&Bsc[row * BK + ((quad ^ (row & 7)) * 8)];
        }
        __builtin_amdgcn_s_setprio(1);
#pragma unroll
        for (int mi = 0; mi < 4; ++mi)
#pragma unroll
            for (int ni = 0; ni < 4; ++ni)
                acc[mi][ni] = __builtin_amdgcn_mfma_f32_16x16x32_f16(
                    a0[mi], bx[ni], acc[mi][ni], 0, 0, 0);
        __builtin_amdgcn_s_setprio(0);

#pragma unroll
        for (int mi = 0; mi < 4; ++mi) {
            int row = wm * 64 + mi * 16 + mlane;
            a1[mi] = *(const f16x8*)&Asc[row * BK + (((4 + quad) ^ (row & 7)) * 8)];
        }
#pragma unroll
        for (int ni = 0; ni < 4; ++ni) {
            int row = wn * 128 + ni * 16 + mlane;
            bx[ni] = *(const f16x8*)&Bsc[row * BK + (((4 + quad) ^ (row & 7)) * 8)];
        }
        __builtin_amdgcn_s_setprio(1);
#pragma unroll
        for (int mi = 0; mi < 4; ++mi)
#pragma unroll
            for (int ni = 0; ni < 4; ++ni)
                acc[mi][ni + 4] = __builtin_amdgcn_mfma_f32_16x16x32_f16(
                    a0[mi], by8[ni], acc[mi][ni + 4], 0, 0, 0);
        __builtin_amdgcn_s_setprio(0);

#pragma unroll
        for (int ni = 0; ni < 4; ++ni) {
            int row = wn * 128 + (ni + 4) * 16 + mlane;
            by8[ni] = *(const f16x8*)&Bsc[row * BK + (((4 + quad) ^ (row & 7)) * 8)];
        }
        __builtin_amdgcn_s_setprio(1);
#pragma unroll
        for (int mi = 0; mi < 4; ++mi)
#pragma unroll
            for (int ni = 0; ni < 4; ++ni)
                acc[mi][ni] = __builtin_amdgcn_mfma_f32_16x16x32_f16(
                    a1[mi], bx[ni], acc[mi][ni], 0, 0, 0);
        __builtin_amdgcn_s_setprio(0);

        __builtin_amdgcn_s_setprio(1);
#pragma unroll
        for (int mi = 0; mi < 4; ++mi)
#pragma unroll
            for (int ni = 0; ni < 4; ++ni)
                acc[mi][ni + 4] = __builtin_amdgcn_mfma_f32_16x16x32_f16(
                    a1[mi], by8[ni], acc[mi][ni + 4], 0, 0, 0);
        __builtin_amdgcn_s_setprio(0);

        // all waves done reading tile t -> safe to overwrite this buffer with tile t+2
        __builtin_amdgcn_s_barrier();
        if (t + 2 < NT) {
            int k0 = (t + 2) * BK;
#pragma unroll
            for (int q = 0; q < 4; ++q)
                __builtin_amdgcn_global_load_lds(
                    (const __attribute__((address_space(1))) void*)(aptr[q] + k0),
                    (__attribute__((address_space(3))) void*)&Ls[cur][0][(q * 512 + wave * 64) * 8],
                    16, 0, 0);
#pragma unroll
            for (int q = 0; q < 4; ++q)
                __builtin_amdgcn_global_load_lds(
                    (const __attribute__((address_space(1))) void*)(bptr[q] + k0),
                    (__attribute__((address_space(3))) void*)&Ls[cur][1][(q * 512 + wave * 64) * 8],
                    16, 0, 0);
        }
        cur ^= 1;
    }

    // C/D layout: col = lane&15 (B-row within 16-tile), row = quad*4 + reg.
    const int p = 2 * by + wn;
    // PU col r at ni=r/16, PV at ni+4 (same lane). T[p][m] = sum_r PU*PV.
#pragma unroll
    for (int mi = 0; mi < 4; ++mi) {
#pragma unroll
        for (int j = 0; j < 4; ++j) {
            float tp = 0.f;
#pragma unroll
            for (int ni = 0; ni < 4; ++ni)
                tp += acc[mi][ni][j] * acc[mi][ni + 4][j];
            tp += __shfl_xor(tp, 1);
            tp += __shfl_xor(tp, 2);
            tp += __shfl_xor(tp, 4);
            tp += __shfl_xor(tp, 8);
            if (mlane == 0) {
                int m = wm * 64 + mi * 16 + quad * 4 + j;
                T[(size_t)p * BDIM + (m0 + m)] = tp;
            }
        }
    }
}

// ---------------- epilogue: gate MFMA + per-row recurrence + scaled write-out ----------------
// Block = 16 batch rows. Phase A: G[16 rows][24 gates] = X0h . Wg^T via one wave of
// 16x16x32 MFMA over LDS-staged k-chunks (512 f16): Xs = 16 rows, Ws = 24 (padded 32,
// pad rows zero-filled once at start - R5 left them uninitialized; outputs from them
// are discarded either way, but zero-fill removes the uninitialized-LDS read).
// Wg rows converted f32->f16 at staging. XOR swizzle (16B chunk c of row r at c^(r&7))
// on LDS writes + fragment reads -> 2-way max bank aliasing (free).
// G is s-independent: Xi = s*X0 -> Xi.Wg = s*(X0.Wg), so logits = s*G + bg per layer.
// Phase B: 16-thread scalar recurrence (reads Gs from LDS, T from global).
// Phase C: out[b] = s_b * X0h[b] bulk write.
__global__ __launch_bounds__(256) void epilogue_kernel(
    const _Float16* __restrict__ X0h,
    const float* __restrict__ T,
    const float* __restrict__ Wg,   // [NP][DDIM] f32
    const float* __restrict__ bg,
    float* __restrict__ out) {
    __shared__ _Float16 Xs[16 * 512];   // 16 KB
    __shared__ _Float16 Ws[32 * 512];   // 32 KB (rows 24-31 = zero pad for the n-tile)
    __shared__ float Gs[16 * NP];
    __shared__ float s_sh[16];

    const int b0 = blockIdx.x * 16;
    const int tid = (int)threadIdx.x;
    const int wave = tid >> 6;
    const int lane = tid & 63;
    const int mlane = lane & 15;
    const int quad = lane >> 4;

    // zero-fill pad rows 24-31 of Ws once (4096 f16 = 512 f16x8 by 256 threads)
#pragma unroll
    for (int t = tid; t < 512; t += 256)
        *(f16x8*)&Ws[24 * 512 + t * 8] = (f16x8){0, 0, 0, 0, 0, 0, 0, 0};

    f32x4 g0 = (f32x4){0.f, 0.f, 0.f, 0.f};
    f32x4 g1 = (f32x4){0.f, 0.f, 0.f, 0.f};

    for (int kc = 0; kc < 4; ++kc) {
        __syncthreads();   // prior chunk's fragment reads done before overwrite
        // stage Xs: 16 rows x 64 16B-chunks
#pragma unroll
        for (int t = tid; t < 1024; t += 256) {
            int r = t >> 6, c = t & 63;
            f16x8 v = *(const f16x8*)&X0h[(size_t)(b0 + r) * DDIM + kc * 512 + c * 8];
            *(f16x8*)&Xs[r * 512 + ((c ^ (r & 7)) * 8)] = v;
        }
        // stage Ws: 24 rows x 128 float4 (f32 -> f16)
#pragma unroll
        for (int t = tid; t < 3072; t += 256) {
            int r = t >> 7, c4 = t & 127;
            float4 v = *(const float4*)&Wg[(size_t)r * DDIM + kc * 512 + c4 * 4];
            f16x4 h = { (_Float16)v.x, (_Float16)v.y, (_Float16)v.z, (_Float16)v.w };
            int chunk = c4 >> 1, half = c4 & 1;
            *(f16x4*)&Ws[r * 512 + (((chunk ^ (r & 7)) * 2 + half) * 4)] = h;
        }
        __syncthreads();
        if (wave == 0) {
#pragma unroll
            for (int ks = 0; ks < 16; ++ks) {
                int lc = ks * 4 + quad;     // logical 16B chunk within the 512-f16 row
                f16x8 af  = *(const f16x8*)&Xs[mlane * 512 + ((lc ^ (mlane & 7)) * 8)];
                f16x8 bf0 = *(const f16x8*)&Ws[mlane * 512 + ((lc ^ (mlane & 7)) * 8)];
                int r1 = 16 + mlane;
                f16x8 bf1 = *(const f16x8*)&Ws[r1 * 512 + ((lc ^ (r1 & 7)) * 8)];
                g0 = __builtin_amdgcn_mfma_f32_16x16x32_f16(af, bf0, g0, 0, 0, 0);
                g1 = __builtin_amdgcn_mfma_f32_16x16x32_f16(af, bf1, g1, 0, 0, 0);
            }
        }
    }
    if (wave == 0) {
        // C layout: col = mlane (gate j), row = quad*4 + reg (batch row)
#pragma unroll
        for (int j = 0; j < 4; ++j) {
            int row = quad * 4 + j;
            Gs[row * NP + mlane] = g0[j];
            if (mlane < 8) Gs[row * NP + 16 + mlane] = g1[j];
        }
    }
    __syncthreads();

    if (tid < 16) {
        int b = b0 + tid;
        float s = 1.f;
#pragma unroll
        for (int l = 0; l < LNUM; ++l) {
            float logit[ENUM];
            float mx = -1e30f;
#pragma unroll
            for (int e = 0; e < ENUM; ++e) {
                int j = l * ENUM + e;
                float g = s * Gs[tid * NP + j] + bg[j];
                logit[e] = g;
                mx = fmaxf(mx, g);
            }
            float den = 0.f, num = 0.f;
            float s2 = s * s;
#pragma unroll
            for (int e = 0; e < ENUM; ++e) {
                int j = l * ENUM + e;
                float w = __expf(logit[e] - mx);
                den += w;
                num += w * (s2 * T[(size_t)j * BDIM + b]);
            }
            s += num / den;
        }
        s_sh[tid] = s;
    }
    __syncthreads();
    const int nf4 = DDIM / 4;   // 512 float4 per row
    for (int idx = tid; idx < 16 * nf4; idx += 256) {
        int r = idx >> 9;
        int c = idx & (nf4 - 1);
        float s = s_sh[r];
        f16x4 h = ((const f16x4*)(X0h + (size_t)(b0 + r) * DDIM))[c];
        float4 x = { s * (float)h[0], s * (float)h[1], s * (float)h[2], s * (float)h[3] };
        ((float4*)(out + (size_t)(b0 + r) * DDIM))[c] = x;
    }
}

extern "C" void kernel_launch(void* const* d_in, const int* in_sizes, int n_in,
                              void* d_out, int out_size, void* d_ws, size_t ws_size,
                              hipStream_t stream) {
    const float* X0 = (const float*)d_in[0];
    const float* U  = (const float*)d_in[1];
    const float* V  = (const float*)d_in[2];
    const float* Wg = (const float*)d_in[3];
    const float* bg = (const float*)d_in[4];
    float* out = (float*)d_out;

    // workspace layout (~81.3 MB)
    char* ws = (char*)d_ws;
    _Float16* X0h = (_Float16*)ws;                                   // 16384*2048*2 = 67108864
    _Float16* Wh  = (_Float16*)(ws + 67108864ull);                   // 24*128*2048*2 = 12582912
    float* T      = (float*)(ws + 79691776ull);                      // 24*16384*4 = 1572864

    cvt_w_kernel<<<dim3((NP * 128 * DDIM / 4) / 256), dim3(256), 0, stream>>>(U, V, Wh);
    cvt_x_kernel<<<dim3((BDIM * DDIM / 4) / 256), dim3(256), 0, stream>>>(X0, X0h);
    gemm_t_kernel<<<dim3(BDIM / BM, 12), dim3(512), 0, stream>>>(X0h, Wh, T);
    epilogue_kernel<<<dim3(BDIM / 16), dim3(256), 0, stream>>>(X0h, T, Wg, bg, out);
}